// Round 1
// baseline (5268.950 us; speedup 1.0000x reference)
//
#include <hip/hip_runtime.h>

// Problem constants (from reference)
#define NC 50000
#define NG 3000
#define D  64

// One fused edge-scatter: out[dst[e]] += (cj[src]*mask[src]*ci[dst]*alpha) * feat[src]
// 16 lanes per edge, float4 per lane -> coalesced 256B row read, 4 atomics/lane.
__global__ __launch_bounds__(256) void edge_scatter_kernel(
    const float* __restrict__ feat,   // [Nsrc, D]
    const float* __restrict__ cj,     // [Nsrc]
    const float* __restrict__ mask,   // [Nsrc]
    const float* __restrict__ ci,     // [Ndst]
    const int*   __restrict__ src,    // [E]
    const int*   __restrict__ dst,    // [E]
    float*       __restrict__ out,    // [Ndst, D]
    int nedges, float alpha)
{
    const int lane16 = threadIdx.x & 15;   // which float4 of the row
    const int eloc   = threadIdx.x >> 4;   // 16 edges per 256-thread block
    const long long e = (long long)blockIdx.x * 16 + eloc;
    if (e >= nedges) return;

    const int s = src[e];
    const int t = dst[e];
    // Per-edge folded weight (all same-address loads broadcast within the wave)
    const float w = cj[s] * mask[s] * ci[t] * alpha;

    const float4 v = *(const float4*)(feat + (size_t)s * D + lane16 * 4);
    float* o = out + (size_t)t * D + lane16 * 4;

#if defined(__HIP_DEVICE_COMPILE__)
    unsafeAtomicAdd(o + 0, w * v.x);
    unsafeAtomicAdd(o + 1, w * v.y);
    unsafeAtomicAdd(o + 2, w * v.z);
    unsafeAtomicAdd(o + 3, w * v.w);
#endif
}

extern "C" void kernel_launch(void* const* d_in, const int* in_sizes, int n_in,
                              void* d_out, int out_size, void* d_ws, size_t ws_size,
                              hipStream_t stream)
{
    const float* c_feat   = (const float*)d_in[0];
    const float* g_feat   = (const float*)d_in[1];
    const float* cj_cell  = (const float*)d_in[2];
    const float* ci_cell  = (const float*)d_in[3];
    const float* cj_gene  = (const float*)d_in[4];
    const float* ci_gene  = (const float*)d_in[5];
    const float* cjj_gene = (const float*)d_in[6];
    const float* cii_gene = (const float*)d_in[7];
    const float* mask_exp = (const float*)d_in[8];
    const float* mask_rev = (const float*)d_in[9];
    const float* mask_gg  = (const float*)d_in[10];
    const int*   src_cg   = (const int*)d_in[11];
    const int*   dst_cg   = (const int*)d_in[12];
    const int*   src_gc   = (const int*)d_in[13];
    const int*   dst_gc   = (const int*)d_in[14];
    const int*   src_gg   = (const int*)d_in[15];
    const int*   dst_gg   = (const int*)d_in[16];

    const int e_cg = in_sizes[11];
    const int e_gc = in_sizes[13];
    const int e_gg = in_sizes[15];

    float* c_out = (float*)d_out;                       // [NC, D]
    float* g_out = (float*)d_out + (size_t)NC * D;      // [NG, D]

    // d_out is poisoned before every call -> zero it (memset node is capture-safe)
    hipMemsetAsync(d_out, 0, (size_t)out_size * sizeof(float), stream);

    // relation 'exp': cell -> gene, alpha1 = 0.5 folded in
    edge_scatter_kernel<<<(e_cg + 15) / 16, 256, 0, stream>>>(
        c_feat, cj_cell, mask_exp, ci_gene, src_cg, dst_cg, g_out, e_cg, 0.5f);

    // relation 'reverse-exp': gene -> cell (only writer of c_out)
    edge_scatter_kernel<<<(e_gc + 15) / 16, 256, 0, stream>>>(
        g_feat, cj_gene, mask_rev, ci_cell, src_gc, dst_gc, c_out, e_gc, 1.0f);

    // relation 'co-exp': gene -> gene, (1 - alpha1) = 0.5 folded in
    edge_scatter_kernel<<<(e_gg + 15) / 16, 256, 0, stream>>>(
        g_feat, cjj_gene, mask_gg, cii_gene, src_gg, dst_gg, g_out, e_gg, 0.5f);
}

// Round 2
// 1116.951 us; speedup vs baseline: 4.7173x; 4.7173x over previous
//
#include <hip/hip_runtime.h>

#define NC 50000
#define NG 3000
#define D  64

// ======================= CSR-build kernels =======================

__global__ __launch_bounds__(256) void weights_kernel(
    const float* __restrict__ cj_cell, const float* __restrict__ mask_exp,
    const float* __restrict__ cj_gene, const float* __restrict__ mask_rev,
    const float* __restrict__ cjj_gene, const float* __restrict__ mask_gg,
    float* __restrict__ w_cell, float* __restrict__ w_gene_rev, float* __restrict__ w_gene_gg)
{
    int i = blockIdx.x * blockDim.x + threadIdx.x;
    if (i < NC) w_cell[i] = cj_cell[i] * mask_exp[i];
    if (i < NG) {
        w_gene_rev[i] = cj_gene[i] * mask_rev[i];
        w_gene_gg[i]  = cjj_gene[i] * mask_gg[i];
    }
}

// Histogram with LDS aggregation (ndst == NG == 3000 fits in 12 KB LDS)
__global__ __launch_bounds__(256) void hist_lds_kernel(
    const int* __restrict__ dst, int* __restrict__ counts, int nedges)
{
    __shared__ int h[NG];
    for (int i = threadIdx.x; i < NG; i += 256) h[i] = 0;
    __syncthreads();
    for (long long e = (long long)blockIdx.x * 256 + threadIdx.x; e < nedges;
         e += (long long)gridDim.x * 256)
        atomicAdd(&h[dst[e]], 1);
    __syncthreads();
    for (int i = threadIdx.x; i < NG; i += 256) {
        int v = h[i];
        if (v) atomicAdd(&counts[i], v);
    }
}

// Plain global histogram (for ndst == NC == 50000)
__global__ __launch_bounds__(256) void hist_global_kernel(
    const int* __restrict__ dst, int* __restrict__ counts, int nedges)
{
    for (long long e = (long long)blockIdx.x * 256 + threadIdx.x; e < nedges;
         e += (long long)gridDim.x * 256)
        atomicAdd(&counts[dst[e]], 1);
}

// Single-block exclusive scan (wave-shuffle based; n up to ~64K)
__global__ __launch_bounds__(1024) void scan_kernel(
    const int* __restrict__ counts, int* __restrict__ offs, int* __restrict__ cursor, int n)
{
    __shared__ int wtot[16];
    __shared__ int woff[16];
    __shared__ int ctot_s;
    __shared__ int carry_s;
    const int tid  = threadIdx.x;
    const int lane = tid & 63;
    const int wid  = tid >> 6;
    if (tid == 0) carry_s = 0;
    __syncthreads();
    for (int base = 0; base < n; base += 1024) {
        int i = base + tid;
        int v = (i < n) ? counts[i] : 0;
        int incl = v;
        #pragma unroll
        for (int d = 1; d < 64; d <<= 1) {
            int t = __shfl_up(incl, d);
            if (lane >= d) incl += t;
        }
        if (lane == 63) wtot[wid] = incl;
        __syncthreads();
        if (wid == 0) {
            int t = (lane < 16) ? wtot[lane] : 0;
            #pragma unroll
            for (int d = 1; d < 16; d <<= 1) {
                int u = __shfl_up(t, d);
                if (lane >= d) t += u;
            }
            if (lane < 16) woff[lane] = t - wtot[lane];
            if (lane == 15) ctot_s = t;
        }
        __syncthreads();
        int excl = incl - v + woff[wid] + carry_s;
        if (i < n) { offs[i] = excl; cursor[i] = excl; }
        __syncthreads();
        if (tid == 0) carry_s += ctot_s;
        __syncthreads();
    }
    if (threadIdx.x == 0) offs[n] = carry_s;
}

__global__ __launch_bounds__(256) void fill_kernel(
    const int* __restrict__ src, const int* __restrict__ dst,
    int* __restrict__ cursor, int* __restrict__ bucket, int nedges)
{
    for (long long e = (long long)blockIdx.x * 256 + threadIdx.x; e < nedges;
         e += (long long)gridDim.x * 256) {
        int pos = atomicAdd(&cursor[dst[e]], 1);
        bucket[pos] = src[e];
    }
}

// ======================= Gather =======================
// One wave per dst row. 4 edges in flight per iteration:
// lanes split into 4 groups of 16; group g handles edge (jj+g), each lane
// holding one float4 (16 B) of the 256 B feature row. Cross-group reduce
// via shfl_xor(16|32) at the end, group 0 writes the row.
template <bool ACC>
__global__ __launch_bounds__(256) void gather_kernel(
    const float* __restrict__ feat, const float* __restrict__ wsrc,
    const float* __restrict__ ci, const int* __restrict__ offs,
    const int* __restrict__ bucket, float* __restrict__ out, int ndst, float alpha)
{
    const int row = blockIdx.x * 4 + (threadIdx.x >> 6);
    if (row >= ndst) return;
    const int lane = threadIdx.x & 63;
    const int grp  = lane >> 4;
    const int l16  = lane & 15;
    const int begin = offs[row], end = offs[row + 1];

    float4 acc = make_float4(0.f, 0.f, 0.f, 0.f);
    for (int jj = begin; jj < end; jj += 4) {
        const int  j     = jj + grp;
        const bool valid = (j < end);
        const int  s     = valid ? bucket[j] : 0;
        const float w    = valid ? wsrc[s] : 0.0f;
        const float4 v = *(const float4*)(feat + (size_t)s * D + l16 * 4);
        acc.x += w * v.x; acc.y += w * v.y; acc.z += w * v.z; acc.w += w * v.w;
    }
    #pragma unroll
    for (int off = 16; off < 64; off <<= 1) {
        acc.x += __shfl_xor(acc.x, off);
        acc.y += __shfl_xor(acc.y, off);
        acc.z += __shfl_xor(acc.z, off);
        acc.w += __shfl_xor(acc.w, off);
    }
    if (grp == 0) {
        const float s_ci = ci[row] * alpha;
        float* o = out + (size_t)row * D + l16 * 4;
        float4 r = make_float4(acc.x * s_ci, acc.y * s_ci, acc.z * s_ci, acc.w * s_ci);
        if (ACC) {
            const float4 prev = *(const float4*)o;
            r.x += prev.x; r.y += prev.y; r.z += prev.z; r.w += prev.w;
        }
        *(float4*)o = r;
    }
}

// ======================= Fallback (round-1 atomic path) =======================

__global__ __launch_bounds__(256) void edge_scatter_kernel(
    const float* __restrict__ feat, const float* __restrict__ cj,
    const float* __restrict__ mask, const float* __restrict__ ci,
    const int* __restrict__ src, const int* __restrict__ dst,
    float* __restrict__ out, int nedges, float alpha)
{
    const int lane16 = threadIdx.x & 15;
    const int eloc   = threadIdx.x >> 4;
    const long long e = (long long)blockIdx.x * 16 + eloc;
    if (e >= nedges) return;
    const int s = src[e];
    const int t = dst[e];
    const float w = cj[s] * mask[s] * ci[t] * alpha;
    const float4 v = *(const float4*)(feat + (size_t)s * D + lane16 * 4);
    float* o = out + (size_t)t * D + lane16 * 4;
#if defined(__HIP_DEVICE_COMPILE__)
    unsafeAtomicAdd(o + 0, w * v.x);
    unsafeAtomicAdd(o + 1, w * v.y);
    unsafeAtomicAdd(o + 2, w * v.z);
    unsafeAtomicAdd(o + 3, w * v.w);
#endif
}

// ======================= Launch =======================

extern "C" void kernel_launch(void* const* d_in, const int* in_sizes, int n_in,
                              void* d_out, int out_size, void* d_ws, size_t ws_size,
                              hipStream_t stream)
{
    const float* c_feat   = (const float*)d_in[0];
    const float* g_feat   = (const float*)d_in[1];
    const float* cj_cell  = (const float*)d_in[2];
    const float* ci_cell  = (const float*)d_in[3];
    const float* cj_gene  = (const float*)d_in[4];
    const float* ci_gene  = (const float*)d_in[5];
    const float* cjj_gene = (const float*)d_in[6];
    const float* cii_gene = (const float*)d_in[7];
    const float* mask_exp = (const float*)d_in[8];
    const float* mask_rev = (const float*)d_in[9];
    const float* mask_gg  = (const float*)d_in[10];
    const int*   src_cg   = (const int*)d_in[11];
    const int*   dst_cg   = (const int*)d_in[12];
    const int*   src_gc   = (const int*)d_in[13];
    const int*   dst_gc   = (const int*)d_in[14];
    const int*   src_gg   = (const int*)d_in[15];
    const int*   dst_gg   = (const int*)d_in[16];

    const int e_cg = in_sizes[11];
    const int e_gc = in_sizes[13];
    const int e_gg = in_sizes[15];

    float* c_out = (float*)d_out;                   // [NC, D]
    float* g_out = (float*)d_out + (size_t)NC * D;  // [NG, D]

    // ---- workspace layout (int units) ----
    int* ws = (int*)d_ws;
    size_t p = 0;
    int* cnt_cg = ws + p; p += NG;
    int* cnt_gc = ws + p; p += NC;
    int* cnt_gg = ws + p; p += NG;          // counts contiguous -> one memset
    int* off_cg = ws + p; p += NG + 1;
    int* off_gc = ws + p; p += NC + 1;
    int* off_gg = ws + p; p += NG + 1;
    int* cur_cg = ws + p; p += NG;
    int* cur_gc = ws + p; p += NC;
    int* cur_gg = ws + p; p += NG;
    float* w_cell     = (float*)(ws + p); p += NC;
    float* w_gene_rev = (float*)(ws + p); p += NG;
    float* w_gene_gg  = (float*)(ws + p); p += NG;
    int* bkt_cg = ws + p; p += e_cg;
    int* bkt_gc = ws + p; p += e_gc;
    int* bkt_gg = ws + p; p += e_gg;
    const size_t need = p * sizeof(int);

    if (need > ws_size) {
        // Fallback: pure atomic scatter (round-1 path)
        hipMemsetAsync(d_out, 0, (size_t)out_size * sizeof(float), stream);
        edge_scatter_kernel<<<(e_cg + 15) / 16, 256, 0, stream>>>(
            c_feat, cj_cell, mask_exp, ci_gene, src_cg, dst_cg, g_out, e_cg, 0.5f);
        edge_scatter_kernel<<<(e_gc + 15) / 16, 256, 0, stream>>>(
            g_feat, cj_gene, mask_rev, ci_cell, src_gc, dst_gc, c_out, e_gc, 1.0f);
        edge_scatter_kernel<<<(e_gg + 15) / 16, 256, 0, stream>>>(
            g_feat, cjj_gene, mask_gg, cii_gene, src_gg, dst_gg, g_out, e_gg, 0.5f);
        return;
    }

    // ---- build CSR per relation ----
    hipMemsetAsync(cnt_cg, 0, (size_t)(NG + NC + NG) * sizeof(int), stream);

    weights_kernel<<<(NC + 255) / 256, 256, 0, stream>>>(
        cj_cell, mask_exp, cj_gene, mask_rev, cjj_gene, mask_gg,
        w_cell, w_gene_rev, w_gene_gg);

    hist_lds_kernel<<<256, 256, 0, stream>>>(dst_cg, cnt_cg, e_cg);
    hist_global_kernel<<<1024, 256, 0, stream>>>(dst_gc, cnt_gc, e_gc);
    hist_lds_kernel<<<64, 256, 0, stream>>>(dst_gg, cnt_gg, e_gg);

    scan_kernel<<<1, 1024, 0, stream>>>(cnt_cg, off_cg, cur_cg, NG);
    scan_kernel<<<1, 1024, 0, stream>>>(cnt_gc, off_gc, cur_gc, NC);
    scan_kernel<<<1, 1024, 0, stream>>>(cnt_gg, off_gg, cur_gg, NG);

    fill_kernel<<<1024, 256, 0, stream>>>(src_cg, dst_cg, cur_cg, bkt_cg, e_cg);
    fill_kernel<<<1024, 256, 0, stream>>>(src_gc, dst_gc, cur_gc, bkt_gc, e_gc);
    fill_kernel<<<256, 256, 0, stream>>>(src_gg, dst_gg, cur_gg, bkt_gg, e_gg);

    // ---- gathers (write every output row -> no d_out memset needed) ----
    gather_kernel<false><<<(NG + 3) / 4, 256, 0, stream>>>(
        c_feat, w_cell, ci_gene, off_cg, bkt_cg, g_out, NG, 0.5f);
    gather_kernel<false><<<(NC + 3) / 4, 256, 0, stream>>>(
        g_feat, w_gene_rev, ci_cell, off_gc, bkt_gc, c_out, NC, 1.0f);
    gather_kernel<true><<<(NG + 3) / 4, 256, 0, stream>>>(
        g_feat, w_gene_gg, cii_gene, off_gg, bkt_gg, g_out, NG, 0.5f);
}